// Round 4
// baseline (12186.667 us; speedup 1.0000x reference)
//
#include <hip/hip_runtime.h>

typedef _Float16 half_t;
typedef _Float16 f16x2 __attribute__((ext_vector_type(2)));
typedef _Float16 f16x8 __attribute__((ext_vector_type(8)));
typedef float f32x4 __attribute__((ext_vector_type(4)));

#define B_SZ 64
#define T_SZ 2048
#define F_SZ 256
#define H_SZ 512
#define O_SZ 128

#if defined(__has_builtin)
#if __has_builtin(__builtin_amdgcn_fdot2)
#define HAS_FDOT2 1
#endif
#endif
#ifndef HAS_FDOT2
#define HAS_FDOT2 0
#endif

static __device__ __forceinline__ float fdot2(unsigned int w, unsigned int h, float acc) {
#if HAS_FDOT2
    return __builtin_amdgcn_fdot2(__builtin_bit_cast(f16x2, w), __builtin_bit_cast(f16x2, h), acc, false);
#else
    f16x2 wv = __builtin_bit_cast(f16x2, w);
    f16x2 hv = __builtin_bit_cast(f16x2, h);
    return acc + (float)wv[0] * (float)hv[0] + (float)wv[1] * (float)hv[1];
#endif
}

static __device__ __forceinline__ unsigned int pack_pair(float a, float b) {
    f16x2 p;
    p[0] = (half_t)a;
    p[1] = (half_t)b;
    return __builtin_bit_cast(unsigned int, p);
}

// ---------------- prep ----------------

__global__ void cvt_f32_f16(const float* __restrict__ src, half_t* __restrict__ dst, int n) {
    int i = blockIdx.x * 256 + threadIdx.x;
    if (i < n) dst[i] = (half_t)src[i];
}

// ---------------- input-projection GEMM (MFMA f16) ----------------
template<bool A_F32, int K>
__global__ __launch_bounds__(256) void gemm_xp(const void* __restrict__ Aptr,
                                               const half_t* __restrict__ Bw,
                                               const float* __restrict__ bias1,
                                               const float* __restrict__ bias2,
                                               half_t* __restrict__ Cout)
{
    const int nt   = blockIdx.x & 7;     // N/64 = 8
    const int mt   = blockIdx.x >> 3;
    const int wave = threadIdx.x >> 6;
    const int lane = threadIdx.x & 63;
    const int mrow = mt * 64 + wave * 16 + (lane & 15);
    const int koff = (lane >> 4) * 8;

    f32x4 acc[4];
#pragma unroll
    for (int i = 0; i < 4; i++) acc[i] = (f32x4){0.f, 0.f, 0.f, 0.f};

#pragma unroll 2
    for (int k0 = 0; k0 < K; k0 += 32) {
        f16x8 a;
        if (A_F32) {
            const float* ap = (const float*)Aptr + (size_t)mrow * K + (k0 + koff);
            float4 v0 = ((const float4*)ap)[0];
            float4 v1 = ((const float4*)ap)[1];
            a[0] = (half_t)v0.x; a[1] = (half_t)v0.y; a[2] = (half_t)v0.z; a[3] = (half_t)v0.w;
            a[4] = (half_t)v1.x; a[5] = (half_t)v1.y; a[6] = (half_t)v1.z; a[7] = (half_t)v1.w;
        } else {
            const half_t* ap = (const half_t*)Aptr + (size_t)mrow * K + (k0 + koff);
            a = *(const f16x8*)ap;
        }
#pragma unroll
        for (int cb = 0; cb < 4; cb++) {
            const int col = nt * 64 + cb * 16 + (lane & 15);
            f16x8 bfrag = *(const f16x8*)(Bw + (size_t)col * K + (k0 + koff));
            acc[cb] = __builtin_amdgcn_mfma_f32_16x16x32_f16(a, bfrag, acc[cb], 0, 0, 0);
        }
    }
    const int rbase = mt * 64 + wave * 16 + (lane >> 4) * 4;
#pragma unroll
    for (int cb = 0; cb < 4; cb++) {
        const int col = nt * 64 + cb * 16 + (lane & 15);
        const float bsum = bias1[col] + bias2[col];
#pragma unroll
        for (int r = 0; r < 4; r++) {
            Cout[(size_t)(rbase + r) * H_SZ + col] = (half_t)(acc[cb][r] + bsum);
        }
    }
}

// ---------------- recurrence: 256 threads, W register-maximal ----------------
// One WG (4 waves, 1 wave/SIMD -> 512-VGPR budget) per batch row.
// Thread (l=tid&63, s=tid>>6): k-slice [128s,128s+128), rows j = 2l+p+128m
// (p in {0,1}, m in 0..3; r = 2m+p). Per row 64 half2 pairs: chunks c=0..12
// (52 pairs) in registers (416 uint total, VGPR+AGPR unified - direct VALU
// operands), c=13..15 (12 pairs) in LDS (24 uint4/thread = 96 KB).
// Per step: 16 b128 h-broadcasts/wave + 24 b128 W-reads/thread... per-CU LDS
// ~2100 cyc; VALU 512 dot2. Partials float2 (2-way bank alias = free).
__global__ __launch_bounds__(256, 1)
void rnn_rec256(half_t* xpres,                  // [B,T,512] xp in (res out in place if store_res)
                const int store_res,
                const float* __restrict__ Whh,  // [512,512] f32
                const float* __restrict__ h0,   // [512]
                float* hT)                      // [B,512] or nullptr
{
    __shared__ __align__(16) half_t h_sh[H_SZ];        // 1 KB
    __shared__ __align__(16) float part[4 * H_SZ];     // 8 KB
    __shared__ __align__(16) uint4 wlds[24 * 256];     // 96 KB

    const int tid = threadIdx.x;
    const int b   = blockIdx.x;
    const int l   = tid & 63;
    const int s   = tid >> 6;

    // ---- one-time: W slices -> 416 regs + 24 uint4 LDS per thread ----
    unsigned int wreg[416];   // [r][c][q] = wreg[r*52 + c*4 + q], pairs k2 = 4c+q
#pragma unroll
    for (int r = 0; r < 8; r++) {
        const int j = 2 * l + (r & 1) + 128 * (r >> 1);
        const float* wrow = Whh + (size_t)j * H_SZ + s * 128;
#pragma unroll
        for (int c = 0; c < 13; c++) {
#pragma unroll
            for (int q = 0; q < 4; q++) {
                const int k2 = 4 * c + q;
                wreg[r * 52 + c * 4 + q] = pack_pair(wrow[2 * k2], wrow[2 * k2 + 1]);
            }
        }
#pragma unroll
        for (int c2 = 0; c2 < 3; c2++) {
            uint4 v;
            unsigned int q[4];
#pragma unroll
            for (int qq = 0; qq < 4; qq++) {
                const int k2 = 52 + c2 * 4 + qq;
                q[qq] = pack_pair(wrow[2 * k2], wrow[2 * k2 + 1]);
            }
            v.x = q[0]; v.y = q[1]; v.z = q[2]; v.w = q[3];
            wlds[(r * 3 + c2) * 256 + tid] = v;
        }
    }
    ((unsigned int*)h_sh)[tid] = pack_pair(h0[2 * tid], h0[2 * tid + 1]);
    __syncthreads();

    const uint4* hs4 = (const uint4*)h_sh + s * 16;    // wave-uniform broadcast base
    unsigned int* xp32 = (unsigned int*)xpres;
    const size_t wbase = (size_t)b * T_SZ * 256 + tid; // word index (2 halves/word)

    unsigned int xpw_next = xp32[wbase];               // prefetch t=0

#pragma unroll 1
    for (int t = 0; t < T_SZ; t++) {
        const unsigned int xpw = xpw_next;
        if (t + 1 < T_SZ) xpw_next = xp32[wbase + (size_t)(t + 1) * 256];

        float acc[8];
#pragma unroll
        for (int r = 0; r < 8; r++) acc[r] = 0.f;

        // register-held W: chunks 0..12
#pragma unroll
        for (int c = 0; c < 13; c++) {
            const uint4 h4 = hs4[c];
#pragma unroll
            for (int r = 0; r < 8; r++) {
                acc[r] = fdot2(wreg[r * 52 + c * 4 + 0], h4.x, acc[r]);
                acc[r] = fdot2(wreg[r * 52 + c * 4 + 1], h4.y, acc[r]);
                acc[r] = fdot2(wreg[r * 52 + c * 4 + 2], h4.z, acc[r]);
                acc[r] = fdot2(wreg[r * 52 + c * 4 + 3], h4.w, acc[r]);
            }
        }
        // LDS-held W: chunks 13..15
#pragma unroll
        for (int c2 = 0; c2 < 3; c2++) {
            const uint4 h4 = hs4[13 + c2];
#pragma unroll
            for (int r = 0; r < 8; r++) {
                const uint4 w = wlds[(r * 3 + c2) * 256 + tid];
                acc[r] = fdot2(w.x, h4.x, acc[r]);
                acc[r] = fdot2(w.y, h4.y, acc[r]);
                acc[r] = fdot2(w.z, h4.z, acc[r]);
                acc[r] = fdot2(w.w, h4.w, acc[r]);
            }
        }

        // partials: float2 per (m) at part[s*512 + 2l + 128m]; 2-way alias = free
#pragma unroll
        for (int m = 0; m < 4; m++) {
            float2 pp;
            pp.x = acc[2 * m];
            pp.y = acc[2 * m + 1];
            *(float2*)&part[s * H_SZ + 2 * l + 128 * m] = pp;
        }
        __syncthreads();   // partials visible; all h_sh reads of this step done

        // reduce: outputs {2tid, 2tid+1}
        float y0 = 0.f, y1 = 0.f;
#pragma unroll
        for (int s2 = 0; s2 < 4; s2++) {
            float2 pp = *(const float2*)&part[s2 * H_SZ + 2 * tid];
            y0 += pp.x;
            y1 += pp.y;
        }
        {
            f16x2 xp2 = __builtin_bit_cast(f16x2, xpw);
            y0 += (float)xp2[0];
            y1 += (float)xp2[1];
        }
        // tanh via exp2-free: 1 - 2/(e^{2y}+1)
        float e0 = __expf(2.0f * y0);
        float e1 = __expf(2.0f * y1);
        float h0n = 1.0f - 2.0f / (e0 + 1.0f);
        float h1n = 1.0f - 2.0f / (e1 + 1.0f);
        unsigned int hw = pack_pair(h0n, h1n);
        ((unsigned int*)h_sh)[tid] = hw;
        if (store_res) xp32[wbase + (size_t)t * 256] = hw;
        if (hT != nullptr && t == T_SZ - 1) {
            float2 o;
            o.x = h0n; o.y = h1n;
            *(float2*)&hT[(size_t)b * H_SZ + 2 * tid] = o;
        }
        __syncthreads();   // h_sh update visible for next step
    }
}

// ---------------- head ----------------
__global__ __launch_bounds__(128) void head_fc(const float* __restrict__ hT,
                                               const float* __restrict__ Wfc,
                                               const float* __restrict__ bfc,
                                               float* __restrict__ out)
{
    __shared__ float hs[H_SZ];
    const int b = blockIdx.x, o = threadIdx.x;
    for (int i = o; i < H_SZ; i += 128) hs[i] = hT[(size_t)b * H_SZ + i];
    __syncthreads();
    const float4* w4 = (const float4*)(Wfc + (size_t)o * H_SZ);
    const float4* h4 = (const float4*)hs;
    float acc = 0.f;
#pragma unroll 4
    for (int k = 0; k < H_SZ / 4; k++) {
        float4 w = w4[k], h = h4[k];
        acc += w.x * h.x + w.y * h.y + w.z * h.z + w.w * h.w;
    }
    out[(size_t)b * O_SZ + o] = acc + bfc[o];
}

// ---------------- launch ----------------

extern "C" void kernel_launch(void* const* d_in, const int* in_sizes, int n_in,
                              void* d_out, int out_size, void* d_ws, size_t ws_size,
                              hipStream_t stream) {
    const float* x     = (const float*)d_in[0];
    const float* W_ih0 = (const float*)d_in[1];
    const float* W_hh0 = (const float*)d_in[2];
    const float* b_ih0 = (const float*)d_in[3];
    const float* b_hh0 = (const float*)d_in[4];
    const float* h0_0  = (const float*)d_in[5];
    const float* W_ih1 = (const float*)d_in[6];
    const float* W_hh1 = (const float*)d_in[7];
    const float* b_ih1 = (const float*)d_in[8];
    const float* b_hh1 = (const float*)d_in[9];
    const float* h0_1  = (const float*)d_in[10];
    const float* W_fc  = (const float*)d_in[11];
    const float* b_fc  = (const float*)d_in[12];

    char* ws = (char*)d_ws;
    size_t off = 0;
    const size_t bufElems = (size_t)B_SZ * T_SZ * H_SZ;          // 67,108,864
    half_t* bufA  = (half_t*)(ws + off); off += bufElems * 2;    // xp0 -> res (in place)
    half_t* bufB  = (half_t*)(ws + off); off += bufElems * 2;    // xp1
    half_t* Wih0h = (half_t*)(ws + off); off += (size_t)H_SZ * F_SZ * 2;
    half_t* Wih1h = (half_t*)(ws + off); off += (size_t)H_SZ * H_SZ * 2;
    float*  hTbuf = (float*)(ws + off);  off += (size_t)B_SZ * H_SZ * 4;

    const int M = B_SZ * T_SZ;   // 131072

    cvt_f32_f16<<<(H_SZ * F_SZ + 255) / 256, 256, 0, stream>>>(W_ih0, Wih0h, H_SZ * F_SZ);
    cvt_f32_f16<<<(H_SZ * H_SZ + 255) / 256, 256, 0, stream>>>(W_ih1, Wih1h, H_SZ * H_SZ);

    // xp0 = x @ W_ih0^T + b_ih0 + b_hh0
    gemm_xp<true, F_SZ><<<(M / 64) * 8, 256, 0, stream>>>(x, Wih0h, b_ih0, b_hh0, bufA);
    // layer-0 recurrence (res overwrites xp0 in place)
    rnn_rec256<<<B_SZ, 256, 0, stream>>>(bufA, 1, W_hh0, h0_0, nullptr);
    // xp1 = res @ W_ih1^T + b_ih1 + b_hh1
    gemm_xp<false, H_SZ><<<(M / 64) * 8, 256, 0, stream>>>(bufA, Wih1h, b_ih1, b_hh1, bufB);
    // layer-1 recurrence, keep only final hidden
    rnn_rec256<<<B_SZ, 256, 0, stream>>>(bufB, 0, W_hh1, h0_1, hTbuf);
    // head
    head_fc<<<B_SZ, 128, 0, stream>>>(hTbuf, W_fc, b_fc, (float*)d_out);
}

// Round 5
// 7849.442 us; speedup vs baseline: 1.5526x; 1.5526x over previous
//
#include <hip/hip_runtime.h>

typedef _Float16 half_t;
typedef _Float16 f16x2 __attribute__((ext_vector_type(2)));
typedef _Float16 f16x8 __attribute__((ext_vector_type(8)));
typedef float f32x4 __attribute__((ext_vector_type(4)));

#define B_SZ 64
#define T_SZ 2048
#define F_SZ 256
#define H_SZ 512
#define O_SZ 128

#if defined(__has_builtin)
#if __has_builtin(__builtin_amdgcn_fdot2)
#define HAS_FDOT2 1
#endif
#if __has_builtin(__builtin_amdgcn_readlane)
#define HAS_READLANE 1
#endif
#endif
#ifndef HAS_FDOT2
#define HAS_FDOT2 0
#endif
#ifndef HAS_READLANE
#define HAS_READLANE 0
#endif

static __device__ __forceinline__ float fdot2(unsigned int w, unsigned int h, float acc) {
#if HAS_FDOT2
    return __builtin_amdgcn_fdot2(__builtin_bit_cast(f16x2, w), __builtin_bit_cast(f16x2, h), acc, false);
#else
    f16x2 wv = __builtin_bit_cast(f16x2, w);
    f16x2 hv = __builtin_bit_cast(f16x2, h);
    return acc + (float)wv[0] * (float)hv[0] + (float)wv[1] * (float)hv[1];
#endif
}

static __device__ __forceinline__ unsigned int pack_pair(float a, float b) {
    f16x2 p;
    p[0] = (half_t)a;
    p[1] = (half_t)b;
    return __builtin_bit_cast(unsigned int, p);
}

static __device__ __forceinline__ unsigned int read_even_lane(unsigned int v, int lane) {
#if HAS_READLANE
    return (unsigned int)__builtin_amdgcn_readlane((int)v, lane);
#else
    return (unsigned int)__shfl((int)v, lane, 64);
#endif
}

// ---------------- prep ----------------

__global__ void cvt_f32_f16(const float* __restrict__ src, half_t* __restrict__ dst, int n) {
    int i = blockIdx.x * 256 + threadIdx.x;
    if (i < n) dst[i] = (half_t)src[i];
}

// ---------------- input-projection GEMM (MFMA f16) ----------------
template<bool A_F32, int K>
__global__ __launch_bounds__(256) void gemm_xp(const void* __restrict__ Aptr,
                                               const half_t* __restrict__ Bw,
                                               const float* __restrict__ bias1,
                                               const float* __restrict__ bias2,
                                               half_t* __restrict__ Cout)
{
    const int nt   = blockIdx.x & 7;     // N/64 = 8
    const int mt   = blockIdx.x >> 3;
    const int wave = threadIdx.x >> 6;
    const int lane = threadIdx.x & 63;
    const int mrow = mt * 64 + wave * 16 + (lane & 15);
    const int koff = (lane >> 4) * 8;

    f32x4 acc[4];
#pragma unroll
    for (int i = 0; i < 4; i++) acc[i] = (f32x4){0.f, 0.f, 0.f, 0.f};

#pragma unroll 2
    for (int k0 = 0; k0 < K; k0 += 32) {
        f16x8 a;
        if (A_F32) {
            const float* ap = (const float*)Aptr + (size_t)mrow * K + (k0 + koff);
            float4 v0 = ((const float4*)ap)[0];
            float4 v1 = ((const float4*)ap)[1];
            a[0] = (half_t)v0.x; a[1] = (half_t)v0.y; a[2] = (half_t)v0.z; a[3] = (half_t)v0.w;
            a[4] = (half_t)v1.x; a[5] = (half_t)v1.y; a[6] = (half_t)v1.z; a[7] = (half_t)v1.w;
        } else {
            const half_t* ap = (const half_t*)Aptr + (size_t)mrow * K + (k0 + koff);
            a = *(const f16x8*)ap;
        }
#pragma unroll
        for (int cb = 0; cb < 4; cb++) {
            const int col = nt * 64 + cb * 16 + (lane & 15);
            f16x8 bfrag = *(const f16x8*)(Bw + (size_t)col * K + (k0 + koff));
            acc[cb] = __builtin_amdgcn_mfma_f32_16x16x32_f16(a, bfrag, acc[cb], 0, 0, 0);
        }
    }
    const int rbase = mt * 64 + wave * 16 + (lane >> 4) * 4;
#pragma unroll
    for (int cb = 0; cb < 4; cb++) {
        const int col = nt * 64 + cb * 16 + (lane & 15);
        const float bsum = bias1[col] + bias2[col];
#pragma unroll
        for (int r = 0; r < 4; r++) {
            Cout[(size_t)(rbase + r) * H_SZ + col] = (half_t)(acc[cb][r] + bsum);
        }
    }
}

// ---------------- recurrence: s-split-8, SGPR h-broadcast, parity partials ----------------
// One WG (512 thr, 8 waves, 2 waves/SIMD) per batch row.
// Wave s, lane l (tid = 64s+l): computes partial dots for rows j = 8l..8l+7
// over k in [64s, 64s+64) (32 half2-pairs/row, 256 pairs/thread).
// W storage: pairs c=0..25 in registers (208), c=26..31 in LDS (12 uint4/thr).
// h path: thread tid computes h[tid] each step; wave s's k-slice h[64s..64s+64)
// IS its own lanes' values -> pack pairs (shfl_xor) + 32 v_readlane -> SGPRs;
// v_dot2 reads h as SGPR broadcast. h never touches LDS.
// Partials: part[par][s][512], 2x float4 write, 8x b32 read; ONE barrier/step
// (parity double-buffer makes write(t+1) safe while stragglers read(t)).
__global__ __launch_bounds__(512, 2)
void rnn_rec8(half_t* xpres,                  // [B,T,512] xp in (res out in place if store_res)
              const int store_res,
              const float* __restrict__ Whh,  // [512,512] f32
              const float* __restrict__ h0,   // [512]
              float* hT)                      // [B,512] or nullptr
{
    __shared__ __align__(16) float part[2][8 * H_SZ];   // 32 KB
    __shared__ __align__(16) uint4 wlds[12 * 512];      // 96 KB

    const int tid = threadIdx.x;
    const int b   = blockIdx.x;
    const int l   = tid & 63;
    const int s   = tid >> 6;

    // ---- one-time: W -> 208 regs + 12 uint4 LDS per thread ----
    unsigned int wreg[208];   // [c][r] = wreg[c*8+r], pair c over k, row r
#pragma unroll
    for (int r = 0; r < 8; r++) {
        const float* wrow = Whh + (size_t)(8 * l + r) * H_SZ + 64 * s;
#pragma unroll
        for (int c = 0; c < 26; c++) {
            wreg[c * 8 + r] = pack_pair(wrow[2 * c], wrow[2 * c + 1]);
        }
    }
#pragma unroll
    for (int p2 = 0; p2 < 6; p2++) {
#pragma unroll
        for (int rh = 0; rh < 2; rh++) {
            unsigned int q[4];
#pragma unroll
            for (int rr = 0; rr < 4; rr++) {
                const int r = rh * 4 + rr;
                const float* wrow = Whh + (size_t)(8 * l + r) * H_SZ + 64 * s;
                const int c = 26 + p2;
                q[rr] = pack_pair(wrow[2 * c], wrow[2 * c + 1]);
            }
            uint4 v;
            v.x = q[0]; v.y = q[1]; v.z = q[2]; v.w = q[3];
            wlds[(p2 * 2 + rh) * 512 + tid] = v;
        }
    }
    float hprev = h0[tid];
    __syncthreads();

    const unsigned short* xp16 = (const unsigned short*)xpres;
    unsigned short* xps = (unsigned short*)xpres;
    const size_t base = (size_t)b * T_SZ * H_SZ + tid;

    unsigned short xpw_next = xp16[base];   // prefetch t=0

#pragma unroll 1
    for (int t = 0; t < T_SZ; t++) {
        // ---- distribute h (prev step) to 32 SGPRs: pack pairs, readlane evens ----
        float hnb = __shfl_xor(hprev, 1, 64);
        unsigned int hw = pack_pair(hprev, hnb);   // even lane 2m: (h[64s+2m], h[64s+2m+1])
        unsigned int hsg[32];
#pragma unroll
        for (int i = 0; i < 32; i++) hsg[i] = read_even_lane(hw, 2 * i);

        const unsigned short xpw = xpw_next;
        if (t + 1 < T_SZ) xpw_next = xp16[base + (size_t)(t + 1) * H_SZ];

        float acc[8];
#pragma unroll
        for (int r = 0; r < 8; r++) acc[r] = 0.f;

        // register-held W: pairs 0..25
#pragma unroll
        for (int c = 0; c < 26; c++) {
            const unsigned int h2 = hsg[c];
#pragma unroll
            for (int r = 0; r < 8; r++) acc[r] = fdot2(wreg[c * 8 + r], h2, acc[r]);
        }
        // LDS-held W: pairs 26..31
#pragma unroll
        for (int p2 = 0; p2 < 6; p2++) {
            const unsigned int h2 = hsg[26 + p2];
            const uint4 w0 = wlds[(p2 * 2 + 0) * 512 + tid];
            const uint4 w1 = wlds[(p2 * 2 + 1) * 512 + tid];
            acc[0] = fdot2(w0.x, h2, acc[0]);
            acc[1] = fdot2(w0.y, h2, acc[1]);
            acc[2] = fdot2(w0.z, h2, acc[2]);
            acc[3] = fdot2(w0.w, h2, acc[3]);
            acc[4] = fdot2(w1.x, h2, acc[4]);
            acc[5] = fdot2(w1.y, h2, acc[5]);
            acc[6] = fdot2(w1.z, h2, acc[6]);
            acc[7] = fdot2(w1.w, h2, acc[7]);
        }

        // partials for rows 8l..8l+7: two float4 stores
        const int par = t & 1;
        {
            float4* pw = (float4*)&part[par][s * H_SZ + 8 * l];
            float4 p0, p1;
            p0.x = acc[0]; p0.y = acc[1]; p0.z = acc[2]; p0.w = acc[3];
            p1.x = acc[4]; p1.y = acc[5]; p1.z = acc[6]; p1.w = acc[7];
            pw[0] = p0;
            pw[1] = p1;
        }
        __syncthreads();   // single barrier: partials(par) visible to all waves

        // reduce output j = tid
        float y;
        {
            half_t xv = __builtin_bit_cast(half_t, xpw);
            y = (float)xv;
        }
#pragma unroll
        for (int s2 = 0; s2 < 8; s2++) y += part[par][s2 * H_SZ + tid];

        // tanh(y) = 1 - 2/(e^{2y}+1)
        float e  = __expf(2.0f * y);
        float hn = 1.0f - 2.0f / (e + 1.0f);
        if (store_res)
            xps[base + (size_t)t * H_SZ] = __builtin_bit_cast(unsigned short, (half_t)hn);
        if (hT != nullptr && t == T_SZ - 1) hT[(size_t)b * H_SZ + tid] = hn;
        hprev = hn;
        // no second barrier: next step's writes go to part[par^1]
    }
}

// ---------------- head ----------------
__global__ __launch_bounds__(128) void head_fc(const float* __restrict__ hT,
                                               const float* __restrict__ Wfc,
                                               const float* __restrict__ bfc,
                                               float* __restrict__ out)
{
    __shared__ float hs[H_SZ];
    const int b = blockIdx.x, o = threadIdx.x;
    for (int i = o; i < H_SZ; i += 128) hs[i] = hT[(size_t)b * H_SZ + i];
    __syncthreads();
    const float4* w4 = (const float4*)(Wfc + (size_t)o * H_SZ);
    const float4* h4 = (const float4*)hs;
    float acc = 0.f;
#pragma unroll 4
    for (int k = 0; k < H_SZ / 4; k++) {
        float4 w = w4[k], h = h4[k];
        acc += w.x * h.x + w.y * h.y + w.z * h.z + w.w * h.w;
    }
    out[(size_t)b * O_SZ + o] = acc + bfc[o];
}

// ---------------- launch ----------------

extern "C" void kernel_launch(void* const* d_in, const int* in_sizes, int n_in,
                              void* d_out, int out_size, void* d_ws, size_t ws_size,
                              hipStream_t stream) {
    const float* x     = (const float*)d_in[0];
    const float* W_ih0 = (const float*)d_in[1];
    const float* W_hh0 = (const float*)d_in[2];
    const float* b_ih0 = (const float*)d_in[3];
    const float* b_hh0 = (const float*)d_in[4];
    const float* h0_0  = (const float*)d_in[5];
    const float* W_ih1 = (const float*)d_in[6];
    const float* W_hh1 = (const float*)d_in[7];
    const float* b_ih1 = (const float*)d_in[8];
    const float* b_hh1 = (const float*)d_in[9];
    const float* h0_1  = (const float*)d_in[10];
    const float* W_fc  = (const float*)d_in[11];
    const float* b_fc  = (const float*)d_in[12];

    char* ws = (char*)d_ws;
    size_t off = 0;
    const size_t bufElems = (size_t)B_SZ * T_SZ * H_SZ;          // 67,108,864
    half_t* bufA  = (half_t*)(ws + off); off += bufElems * 2;    // xp0 -> res (in place)
    half_t* bufB  = (half_t*)(ws + off); off += bufElems * 2;    // xp1
    half_t* Wih0h = (half_t*)(ws + off); off += (size_t)H_SZ * F_SZ * 2;
    half_t* Wih1h = (half_t*)(ws + off); off += (size_t)H_SZ * H_SZ * 2;
    float*  hTbuf = (float*)(ws + off);  off += (size_t)B_SZ * H_SZ * 4;

    const int M = B_SZ * T_SZ;   // 131072

    cvt_f32_f16<<<(H_SZ * F_SZ + 255) / 256, 256, 0, stream>>>(W_ih0, Wih0h, H_SZ * F_SZ);
    cvt_f32_f16<<<(H_SZ * H_SZ + 255) / 256, 256, 0, stream>>>(W_ih1, Wih1h, H_SZ * H_SZ);

    // xp0 = x @ W_ih0^T + b_ih0 + b_hh0
    gemm_xp<true, F_SZ><<<(M / 64) * 8, 256, 0, stream>>>(x, Wih0h, b_ih0, b_hh0, bufA);
    // layer-0 recurrence (res overwrites xp0 in place)
    rnn_rec8<<<B_SZ, 512, 0, stream>>>(bufA, 1, W_hh0, h0_0, nullptr);
    // xp1 = res @ W_ih1^T + b_ih1 + b_hh1
    gemm_xp<false, H_SZ><<<(M / 64) * 8, 256, 0, stream>>>(bufA, Wih1h, b_ih1, b_hh1, bufB);
    // layer-1 recurrence, keep only final hidden
    rnn_rec8<<<B_SZ, 512, 0, stream>>>(bufB, 0, W_hh1, h0_1, hTbuf);
    // head
    head_fc<<<B_SZ, 128, 0, stream>>>(hTbuf, W_fc, b_fc, (float*)d_out);
}

// Round 6
// 4277.555 us; speedup vs baseline: 2.8490x; 1.8350x over previous
//
#include <hip/hip_runtime.h>

typedef _Float16 half_t;
typedef _Float16 f16x2 __attribute__((ext_vector_type(2)));
typedef _Float16 f16x8 __attribute__((ext_vector_type(8)));
typedef float f32x4 __attribute__((ext_vector_type(4)));

#define B_SZ 64
#define T_SZ 2048
#define F_SZ 256
#define H_SZ 512
#define O_SZ 128
#define NCH 32      // chunks
#define CH 64       // timesteps per chunk

#if defined(__has_builtin)
#if __has_builtin(__builtin_amdgcn_fdot2)
#define HAS_FDOT2 1
#endif
#if __has_builtin(__builtin_amdgcn_readlane)
#define HAS_READLANE 1
#endif
#endif
#ifndef HAS_FDOT2
#define HAS_FDOT2 0
#endif
#ifndef HAS_READLANE
#define HAS_READLANE 0
#endif

static __device__ __forceinline__ float fdot2(unsigned int w, unsigned int h, float acc) {
#if HAS_FDOT2
    return __builtin_amdgcn_fdot2(__builtin_bit_cast(f16x2, w), __builtin_bit_cast(f16x2, h), acc, false);
#else
    f16x2 wv = __builtin_bit_cast(f16x2, w);
    f16x2 hv = __builtin_bit_cast(f16x2, h);
    return acc + (float)wv[0] * (float)hv[0] + (float)wv[1] * (float)hv[1];
#endif
}

static __device__ __forceinline__ unsigned int pack_pair(float a, float b) {
    f16x2 p;
    p[0] = (half_t)a;
    p[1] = (half_t)b;
    return __builtin_bit_cast(unsigned int, p);
}

static __device__ __forceinline__ unsigned int read_even_lane(unsigned int v, int lane) {
#if HAS_READLANE
    return (unsigned int)__builtin_amdgcn_readlane((int)v, lane);
#else
    return (unsigned int)__shfl((int)v, lane, 64);
#endif
}

// ---------------- prep ----------------

__global__ void cvt_f32_f16(const float* __restrict__ src, half_t* __restrict__ dst, int n) {
    int i = blockIdx.x * 256 + threadIdx.x;
    if (i < n) dst[i] = (half_t)src[i];
}

__global__ void zero_flags(unsigned int* __restrict__ p, int n) {
    int i = blockIdx.x * 256 + threadIdx.x;
    if (i < n) p[i] = 0u;
}

// ---------------- xp0 GEMM (MFMA f16), layer-0 input projection ----------------
template<bool A_F32, int K>
__global__ __launch_bounds__(256) void gemm_xp(const void* __restrict__ Aptr,
                                               const half_t* __restrict__ Bw,
                                               const float* __restrict__ bias1,
                                               const float* __restrict__ bias2,
                                               half_t* __restrict__ Cout)
{
    const int nt   = blockIdx.x & 7;
    const int mt   = blockIdx.x >> 3;
    const int wave = threadIdx.x >> 6;
    const int lane = threadIdx.x & 63;
    const int mrow = mt * 64 + wave * 16 + (lane & 15);
    const int koff = (lane >> 4) * 8;

    f32x4 acc[4];
#pragma unroll
    for (int i = 0; i < 4; i++) acc[i] = (f32x4){0.f, 0.f, 0.f, 0.f};

#pragma unroll 2
    for (int k0 = 0; k0 < K; k0 += 32) {
        f16x8 a;
        if (A_F32) {
            const float* ap = (const float*)Aptr + (size_t)mrow * K + (k0 + koff);
            float4 v0 = ((const float4*)ap)[0];
            float4 v1 = ((const float4*)ap)[1];
            a[0] = (half_t)v0.x; a[1] = (half_t)v0.y; a[2] = (half_t)v0.z; a[3] = (half_t)v0.w;
            a[4] = (half_t)v1.x; a[5] = (half_t)v1.y; a[6] = (half_t)v1.z; a[7] = (half_t)v1.w;
        } else {
            const half_t* ap = (const half_t*)Aptr + (size_t)mrow * K + (k0 + koff);
            a = *(const f16x8*)ap;
        }
#pragma unroll
        for (int cb = 0; cb < 4; cb++) {
            const int col = nt * 64 + cb * 16 + (lane & 15);
            f16x8 bfrag = *(const f16x8*)(Bw + (size_t)col * K + (k0 + koff));
            acc[cb] = __builtin_amdgcn_mfma_f32_16x16x32_f16(a, bfrag, acc[cb], 0, 0, 0);
        }
    }
    const int rbase = mt * 64 + wave * 16 + (lane >> 4) * 4;
#pragma unroll
    for (int cb = 0; cb < 4; cb++) {
        const int col = nt * 64 + cb * 16 + (lane & 15);
        const float bsum = bias1[col] + bias2[col];
#pragma unroll
        for (int r = 0; r < 4; r++) {
            Cout[(size_t)(rbase + r) * H_SZ + col] = (half_t)(acc[cb][r] + bsum);
        }
    }
}

// ---------------- mega-kernel: pipelined 2-layer RNN ----------------
// 192 blocks x 512 threads, role = blockIdx.x % 3, b = blockIdx.x / 3:
//  role 0: layer-0 recurrence on bufA (xp0 -> res in place); releases
//          flags0[b][chunk] after each 64-step chunk (agent scope).
//  role 1: xp1 producer: polls flags0, MFMA-GEMMs res chunk @ W_ih1^T + bias
//          into bufB, releases flags1[b][chunk]. Lean registers.
//  role 2: layer-1 recurrence on bufB; polls flags1; writes hT at t=T-1.
// Rec inner loop identical to round 5 (s-split-8, SGPR h-broadcast via
// readlane, 208 reg + 12 LDS-uint4 W split, parity partials, 1 barrier/step).
__global__ __launch_bounds__(512, 2)
void rnn_mega(half_t* bufA, half_t* bufB,
              const float* __restrict__ Whh0, const float* __restrict__ Whh1,
              const half_t* __restrict__ Wih1h,
              const float* __restrict__ h0_0, const float* __restrict__ h0_1,
              const float* __restrict__ b_ih1, const float* __restrict__ b_hh1,
              float* hT,
              unsigned int* flags0, unsigned int* flags1)
{
    __shared__ __align__(16) float part[2][8 * H_SZ];   // 32 KB
    __shared__ __align__(16) uint4 wlds[12 * 512];      // 96 KB

    const int role = blockIdx.x % 3;
    const int b    = blockIdx.x / 3;
    const int tid  = threadIdx.x;
    const int l    = tid & 63;
    const int s    = tid >> 6;

    if (role == 1) {
        // ---------- xp1 chunk-GEMM producer ----------
        const int w = s, lane = l;
        const int koff = (lane >> 4) * 8;
        for (int chunk = 0; chunk < NCH; chunk++) {
            if (tid == 0) {
                while (__hip_atomic_load(&flags0[b * NCH + chunk], __ATOMIC_ACQUIRE,
                                         __HIP_MEMORY_SCOPE_AGENT) == 0u)
                    __builtin_amdgcn_s_sleep(2);
            }
            __syncthreads();   // all threads gated; acquire-inv done by wave 0
            const int t0 = chunk * CH;

            f32x4 gac[4][4];
#pragma unroll
            for (int rt = 0; rt < 4; rt++)
#pragma unroll
                for (int cb = 0; cb < 4; cb++) gac[rt][cb] = (f32x4){0.f, 0.f, 0.f, 0.f};

#pragma unroll 1
            for (int k0 = 0; k0 < H_SZ; k0 += 32) {
                f16x8 bf[4];
#pragma unroll
                for (int cb = 0; cb < 4; cb++)
                    bf[cb] = *(const f16x8*)(Wih1h +
                              (size_t)(64 * w + 16 * cb + (lane & 15)) * H_SZ + k0 + koff);
#pragma unroll
                for (int rt = 0; rt < 4; rt++) {
                    const f16x8 a = *(const f16x8*)((const half_t*)bufA +
                              ((size_t)b * T_SZ + t0 + rt * 16 + (lane & 15)) * H_SZ + k0 + koff);
#pragma unroll
                    for (int cb = 0; cb < 4; cb++)
                        gac[rt][cb] = __builtin_amdgcn_mfma_f32_16x16x32_f16(a, bf[cb], gac[rt][cb], 0, 0, 0);
                }
            }
#pragma unroll
            for (int rt = 0; rt < 4; rt++) {
                const int rbase = t0 + rt * 16 + (lane >> 4) * 4;
#pragma unroll
                for (int cb = 0; cb < 4; cb++) {
                    const int col = 64 * w + 16 * cb + (lane & 15);
                    const float bsum = b_ih1[col] + b_hh1[col];
#pragma unroll
                    for (int r = 0; r < 4; r++)
                        bufB[((size_t)b * T_SZ + rbase + r) * H_SZ + col] =
                            (half_t)(gac[rt][cb][r] + bsum);
                }
            }
            __syncthreads();   // drain all waves' bufB stores (vmcnt0 at barrier)
            if (tid == 0)
                __hip_atomic_store(&flags1[b * NCH + chunk], 1u, __ATOMIC_RELEASE,
                                   __HIP_MEMORY_SCOPE_AGENT);
        }
        return;
    }

    // ---------- recurrence (roles 0 and 2) ----------
    const bool L1 = (role == 2);
    const float* Whh = L1 ? Whh1 : Whh0;

    unsigned int wreg[208];   // [c][r] = wreg[c*8+r]
#pragma unroll
    for (int r = 0; r < 8; r++) {
        const float* wrow = Whh + (size_t)(8 * l + r) * H_SZ + 64 * s;
#pragma unroll
        for (int c = 0; c < 26; c++)
            wreg[c * 8 + r] = pack_pair(wrow[2 * c], wrow[2 * c + 1]);
    }
#pragma unroll
    for (int p2 = 0; p2 < 6; p2++) {
#pragma unroll
        for (int rh = 0; rh < 2; rh++) {
            unsigned int q[4];
#pragma unroll
            for (int rr = 0; rr < 4; rr++) {
                const int r = rh * 4 + rr;
                const float* wrow = Whh + (size_t)(8 * l + r) * H_SZ + 64 * s;
                const int c = 26 + p2;
                q[rr] = pack_pair(wrow[2 * c], wrow[2 * c + 1]);
            }
            uint4 v;
            v.x = q[0]; v.y = q[1]; v.z = q[2]; v.w = q[3];
            wlds[(p2 * 2 + rh) * 512 + tid] = v;
        }
    }
    float hprev = (L1 ? h0_1 : h0_0)[tid];
    __syncthreads();

    unsigned short* xp16 = (unsigned short*)(L1 ? bufB : bufA);
    const size_t base = (size_t)b * T_SZ * H_SZ + tid;

#pragma unroll 1
    for (int chunk = 0; chunk < NCH; chunk++) {
        const int t0 = chunk * CH;
        if (L1) {
            if (tid == 0) {
                while (__hip_atomic_load(&flags1[b * NCH + chunk], __ATOMIC_ACQUIRE,
                                         __HIP_MEMORY_SCOPE_AGENT) == 0u)
                    __builtin_amdgcn_s_sleep(2);
            }
            __syncthreads();
        }
        unsigned short xpw_next = xp16[base + (size_t)t0 * H_SZ];

#pragma unroll 1
        for (int tt = 0; tt < CH; tt++) {
            const int t = t0 + tt;
            // distribute h to 32 SGPRs
            float hnb = __shfl_xor(hprev, 1, 64);
            unsigned int hw = pack_pair(hprev, hnb);
            unsigned int hsg[32];
#pragma unroll
            for (int i = 0; i < 32; i++) hsg[i] = read_even_lane(hw, 2 * i);

            const unsigned short xpw = xpw_next;
            if (tt + 1 < CH) xpw_next = xp16[base + (size_t)(t + 1) * H_SZ];

            float acc[8];
#pragma unroll
            for (int r = 0; r < 8; r++) acc[r] = 0.f;

#pragma unroll
            for (int c = 0; c < 26; c++) {
                const unsigned int h2 = hsg[c];
#pragma unroll
                for (int r = 0; r < 8; r++) acc[r] = fdot2(wreg[c * 8 + r], h2, acc[r]);
            }
#pragma unroll
            for (int p2 = 0; p2 < 6; p2++) {
                const unsigned int h2 = hsg[26 + p2];
                const uint4 w0 = wlds[(p2 * 2 + 0) * 512 + tid];
                const uint4 w1 = wlds[(p2 * 2 + 1) * 512 + tid];
                acc[0] = fdot2(w0.x, h2, acc[0]);
                acc[1] = fdot2(w0.y, h2, acc[1]);
                acc[2] = fdot2(w0.z, h2, acc[2]);
                acc[3] = fdot2(w0.w, h2, acc[3]);
                acc[4] = fdot2(w1.x, h2, acc[4]);
                acc[5] = fdot2(w1.y, h2, acc[5]);
                acc[6] = fdot2(w1.z, h2, acc[6]);
                acc[7] = fdot2(w1.w, h2, acc[7]);
            }

            const int par = t & 1;
            {
                float4* pw = (float4*)&part[par][s * H_SZ + 8 * l];
                float4 p0, p1;
                p0.x = acc[0]; p0.y = acc[1]; p0.z = acc[2]; p0.w = acc[3];
                p1.x = acc[4]; p1.y = acc[5]; p1.z = acc[6]; p1.w = acc[7];
                pw[0] = p0;
                pw[1] = p1;
            }
            __syncthreads();

            float y;
            {
                half_t xv = __builtin_bit_cast(half_t, xpw);
                y = (float)xv;
            }
#pragma unroll
            for (int s2 = 0; s2 < 8; s2++) y += part[par][s2 * H_SZ + tid];

            float e  = __expf(2.0f * y);
            float hn = 1.0f - 2.0f / (e + 1.0f);
            if (!L1)
                xp16[base + (size_t)t * H_SZ] = __builtin_bit_cast(unsigned short, (half_t)hn);
            else if (t == T_SZ - 1)
                hT[(size_t)b * H_SZ + tid] = hn;
            hprev = hn;
        }
        if (!L1) {
            __syncthreads();   // drain this chunk's res stores (vmcnt0 at barrier)
            if (tid == 0)
                __hip_atomic_store(&flags0[b * NCH + chunk], 1u, __ATOMIC_RELEASE,
                                   __HIP_MEMORY_SCOPE_AGENT);
        }
    }
}

// ---------------- head ----------------
__global__ __launch_bounds__(128) void head_fc(const float* __restrict__ hT,
                                               const float* __restrict__ Wfc,
                                               const float* __restrict__ bfc,
                                               float* __restrict__ out)
{
    __shared__ float hs[H_SZ];
    const int b = blockIdx.x, o = threadIdx.x;
    for (int i = o; i < H_SZ; i += 128) hs[i] = hT[(size_t)b * H_SZ + i];
    __syncthreads();
    const float4* w4 = (const float4*)(Wfc + (size_t)o * H_SZ);
    const float4* h4 = (const float4*)hs;
    float acc = 0.f;
#pragma unroll 4
    for (int k = 0; k < H_SZ / 4; k++) {
        float4 w = w4[k], h = h4[k];
        acc += w.x * h.x + w.y * h.y + w.z * h.z + w.w * h.w;
    }
    out[(size_t)b * O_SZ + o] = acc + bfc[o];
}

// ---------------- launch ----------------

extern "C" void kernel_launch(void* const* d_in, const int* in_sizes, int n_in,
                              void* d_out, int out_size, void* d_ws, size_t ws_size,
                              hipStream_t stream) {
    const float* x     = (const float*)d_in[0];
    const float* W_ih0 = (const float*)d_in[1];
    const float* W_hh0 = (const float*)d_in[2];
    const float* b_ih0 = (const float*)d_in[3];
    const float* b_hh0 = (const float*)d_in[4];
    const float* h0_0  = (const float*)d_in[5];
    const float* W_ih1 = (const float*)d_in[6];
    const float* W_hh1 = (const float*)d_in[7];
    const float* b_ih1 = (const float*)d_in[8];
    const float* b_hh1 = (const float*)d_in[9];
    const float* h0_1  = (const float*)d_in[10];
    const float* W_fc  = (const float*)d_in[11];
    const float* b_fc  = (const float*)d_in[12];

    char* ws = (char*)d_ws;
    size_t off = 0;
    const size_t bufElems = (size_t)B_SZ * T_SZ * H_SZ;          // 67,108,864
    half_t* bufA  = (half_t*)(ws + off); off += bufElems * 2;    // xp0 -> res (in place)
    half_t* bufB  = (half_t*)(ws + off); off += bufElems * 2;    // xp1 (per-chunk producer)
    half_t* Wih0h = (half_t*)(ws + off); off += (size_t)H_SZ * F_SZ * 2;
    half_t* Wih1h = (half_t*)(ws + off); off += (size_t)H_SZ * H_SZ * 2;
    float*  hTbuf = (float*)(ws + off);  off += (size_t)B_SZ * H_SZ * 4;
    const int FLAG_N = B_SZ * NCH;
    unsigned int* flags0 = (unsigned int*)(ws + off); off += (size_t)FLAG_N * 4;
    unsigned int* flags1 = (unsigned int*)(ws + off); off += (size_t)FLAG_N * 4;

    const int M = B_SZ * T_SZ;   // 131072

    zero_flags<<<(2 * FLAG_N + 255) / 256, 256, 0, stream>>>(flags0, 2 * FLAG_N);
    cvt_f32_f16<<<(H_SZ * F_SZ + 255) / 256, 256, 0, stream>>>(W_ih0, Wih0h, H_SZ * F_SZ);
    cvt_f32_f16<<<(H_SZ * H_SZ + 255) / 256, 256, 0, stream>>>(W_ih1, Wih1h, H_SZ * H_SZ);

    // xp0 = x @ W_ih0^T + b_ih0 + b_hh0
    gemm_xp<true, F_SZ><<<(M / 64) * 8, 256, 0, stream>>>(x, Wih0h, b_ih0, b_hh0, bufA);

    // pipelined: layer-0 rec + xp1 producer + layer-1 rec, all concurrent
    rnn_mega<<<192, 512, 0, stream>>>(bufA, bufB, W_hh0, W_hh1, Wih1h,
                                      h0_0, h0_1, b_ih1, b_hh1,
                                      hTbuf, flags0, flags1);

    head_fc<<<B_SZ, 128, 0, stream>>>(hTbuf, W_fc, b_fc, (float*)d_out);
}